// Round 4
// baseline (122.299 us; speedup 1.0000x reference)
//
#include <hip/hip_runtime.h>
#include <hip/hip_bf16.h>

// Analytical collapse:
//   conv output scores has shape (B, 1, L); softmax over the singleton
//   channel axis is EXACTLY 1.0 -> probs = ones(B, L). Embedding gather
//   and conv1d are dead computation.
//   lax.top_k on an all-equal row tie-breaks by lowest index ->
//   top_idx = [0..383] for every row.
//   => ids_out  = input_ids[:, :384]
//      mask_out = attention_mask[:, :384]
//      probs_sum = 384.0 per row
//
// Output encoding (learned from round-3 failure): the harness reads the
// flat tuple buffer as FLOAT32 ("else float*" path). Round-3's int32
// writes decoded as denormals ~0 -> absmax == max|ref| == 30464. So all
// outputs are written as float32; token ids < 30527 << 2^24 are exactly
// representable.

static constexpr int B = 64;
static constexpr int L = 1024;
static constexpr int K = 384;           // LIMIT
static constexpr int BK = B * K;        // 24576 elements per (B,K) output

// Each thread converts+moves one int4 (4 ids + 4 masks) -> two float4 stores.
__global__ void removal_slice_kernel(const int* __restrict__ ids,
                                     const int* __restrict__ mask,
                                     float* __restrict__ out) {
    const int i = blockIdx.x * blockDim.x + threadIdx.x;   // int4 index
    constexpr int Q = K / 4;            // 96 int4 per row
    constexpr int NV = B * Q;           // 6144 int4 per output tensor
    if (i < NV) {
        const int b = i / Q;
        const int q = i - b * Q;
        const int4 v_ids  = *reinterpret_cast<const int4*>(ids  + b * L + q * 4);
        const int4 v_mask = *reinterpret_cast<const int4*>(mask + b * L + q * 4);
        float4 f_ids, f_mask;
        f_ids.x  = (float)v_ids.x;  f_ids.y  = (float)v_ids.y;
        f_ids.z  = (float)v_ids.z;  f_ids.w  = (float)v_ids.w;
        f_mask.x = (float)v_mask.x; f_mask.y = (float)v_mask.y;
        f_mask.z = (float)v_mask.z; f_mask.w = (float)v_mask.w;
        *reinterpret_cast<float4*>(out + b * K + q * 4)      = f_ids;
        *reinterpret_cast<float4*>(out + BK + b * K + q * 4) = f_mask;
    }
    // probs_sum: B rows, each exactly 384.0f (sum of 384 ones)
    if (i < B) {
        out[2 * BK + i] = (float)K;
    }
}

extern "C" void kernel_launch(void* const* d_in, const int* in_sizes, int n_in,
                              void* d_out, int out_size, void* d_ws, size_t ws_size,
                              hipStream_t stream) {
    const int* input_ids      = (const int*)d_in[0];
    const int* attention_mask = (const int*)d_in[1];
    // d_in[2..4] (emb_table, conv_w, conv_b) are mathematically dead.
    float* out = (float*)d_out;

    constexpr int NV = B * (K / 4);     // 6144 threads needed
    const int block = 256;
    const int grid  = (NV + block - 1) / block;   // 24 blocks
    removal_slice_kernel<<<grid, block, 0, stream>>>(input_ids, attention_mask, out);
}